// Round 8
// baseline (209.420 us; speedup 1.0000x reference)
//
#include <hip/hip_runtime.h>
#include <hip/hip_bf16.h>

// AFT-Full: B=4, T=2048, DIM=1024, HID=256
// All GEMMs: 128x128 tile, BK=64 (A/B-test: halve iteration count vs BK=32 to
// probe the ~2000cy/iter invariant), single-buffer LDS 32KB, 4 waves (2x2),
// 4x4 acc; per iter: 8 gld16 + 16 ds_read_b128 + 32 MFMA + 1 vmcnt(0)+2 barriers.
//   prep      : xb=bf16(x); ewb=bf16(exp(wbias)); WqkvT interleaved (0..255=Q,
//               256+2h=K_h, 257+2h=V_h); WpT[d][h]=Wp[h][d]; biascat
//   gemm1_qkv : [8192x768] = xb @ WqkvT^T + biascat. Fused epilogue:
//               Q cols -> sgQ f32 = sigmoid(q); KV cols -> shfl-pair ->
//               B2T bf16 rows b*512+2h = exp(K)*V (num), b*512+2h+1 = exp(K) (den)
//   gemm2     : C2 = ewb @ B2T^T (full K=2048, no split-K: R3/R7 A/B proved
//               block-count invariance, split-K only added 96MB traffic)
//   elt2      : Yt bf16[8192][256] = sgQ * num/den
//   gemm3     : out = Yt @ WpT^T + bp -> f32 [8192][1024]
// Workspace (62 MB, non-overlapping; ws ~268 MB proven by harness fill):
//   xb 0..16M | C2 16M..32M | ewb 32M..40M | WqkvT +1.5M | WpT +0.5M |
//   biascat +4K | sgQ +8M | B2T +8M | Yt +4M

typedef __attribute__((ext_vector_type(8))) short bf16x8;
typedef __attribute__((ext_vector_type(4))) float f32x4;

static __device__ __forceinline__ unsigned short f2b(float f) {
  __hip_bfloat16 h = __float2bfloat16(f);
  return __builtin_bit_cast(unsigned short, h);
}

static __device__ __forceinline__ void gld16(const void* g, const void* l) {
  __builtin_amdgcn_global_load_lds((const __attribute__((address_space(1))) void*)g,
                                   (__attribute__((address_space(3))) void*)l, 16, 0, 0);
}

// BK=64 core: BM=BN=128. LDS row stride 128B, linear. Staging: 1024 16B-units
// per 16KB tile; thread covers units {tid + 256*i}: row = (tid>>3)+32*i,
// k16 = tid&7 (constant per thread), lds byte = tid*16 + 4096*i.
static __device__ __forceinline__ void core128_bk64(
    const unsigned short* __restrict__ A_blk,
    const unsigned short* __restrict__ Bt_blk,
    long sA, long sB, int nk, char* AsB, char* BsB, f32x4 acc[4][4],
    int tid, int wr, int wc, int fr, int fkb)
{
  const int srow = tid >> 3;
  const int sk   = (tid & 7) * 8;
  const unsigned short* ap0 = A_blk + (long)srow * sA + sk;
  const unsigned short* ap1 = ap0 + 32 * sA;
  const unsigned short* ap2 = ap0 + 64 * sA;
  const unsigned short* ap3 = ap0 + 96 * sA;
  const unsigned short* bp0 = Bt_blk + (long)srow * sB + sk;
  const unsigned short* bp1 = bp0 + 32 * sB;
  const unsigned short* bp2 = bp0 + 64 * sB;
  const unsigned short* bp3 = bp0 + 96 * sB;
  char* la = AsB + tid * 16;
  char* lb = BsB + tid * 16;

  for (int kt = 0; kt < nk; ++kt) {
    gld16(ap0, la);
    gld16(ap1, la + 4096);
    gld16(ap2, la + 8192);
    gld16(ap3, la + 12288);
    gld16(bp0, lb);
    gld16(bp1, lb + 4096);
    gld16(bp2, lb + 8192);
    gld16(bp3, lb + 12288);
    ap0 += 64; ap1 += 64; ap2 += 64; ap3 += 64;
    bp0 += 64; bp1 += 64; bp2 += 64; bp3 += 64;
    asm volatile("s_waitcnt vmcnt(0)" ::: "memory");
    __syncthreads();

#pragma unroll
    for (int kk = 0; kk < 2; ++kk) {
      bf16x8 av[4], bv[4];
#pragma unroll
      for (int m = 0; m < 4; ++m)
        av[m] = *(const bf16x8*)(AsB + (wr * 64 + m * 16 + fr) * 128 + kk * 64 + fkb);
#pragma unroll
      for (int n = 0; n < 4; ++n)
        bv[n] = *(const bf16x8*)(BsB + (wc * 64 + n * 16 + fr) * 128 + kk * 64 + fkb);
#pragma unroll
      for (int m = 0; m < 4; ++m)
#pragma unroll
        for (int n = 0; n < 4; ++n)
          acc[m][n] = __builtin_amdgcn_mfma_f32_16x16x32_bf16(av[m], bv[n], acc[m][n], 0, 0, 0);
    }
    __syncthreads();
  }
}

// Generic C = A @ Bt^T (+bias)
__global__ __launch_bounds__(256) void gemm_bt(
    const unsigned short* __restrict__ A, const unsigned short* __restrict__ Bt,
    float* __restrict__ C, const float* __restrict__ bias, int M, int N, int K)
{
  __shared__ char AsB[16384];
  __shared__ char BsB[16384];
  const int tid = threadIdx.x, lane = tid & 63, wave = tid >> 6;
  const int wr = wave >> 1, wc = wave & 1;
  const int fr = lane & 15, fkb = (lane >> 4) * 16, q4 = (lane >> 4) * 4;
  const long bm = (long)blockIdx.y * 128;
  const long bn = (long)blockIdx.x * 128;

  f32x4 acc[4][4] = {};
  core128_bk64(A + bm * K, Bt + bn * K, K, K, K >> 6,
               AsB, BsB, acc, tid, wr, wc, fr, fkb);

  const long crow0 = bm + wr * 64 + q4;
  const long ccol0 = bn + wc * 64 + fr;
#pragma unroll
  for (int n = 0; n < 4; ++n) {
    const long col = ccol0 + n * 16;
    const float bb = bias ? bias[col] : 0.f;
#pragma unroll
    for (int m = 0; m < 4; ++m)
#pragma unroll
      for (int r = 0; r < 4; ++r)
        C[(crow0 + m * 16 + r) * (long)N + col] = acc[m][n][r] + bb;
  }
}

// gemm1: QKV projection with fused sigmoid / exp / transpose epilogue
__global__ __launch_bounds__(256) void gemm1_qkv(
    const unsigned short* __restrict__ xb, const unsigned short* __restrict__ WqkvT,
    const float* __restrict__ biascat,
    float* __restrict__ sgQ, unsigned short* __restrict__ B2T)
{
  __shared__ char AsB[16384];
  __shared__ char BsB[16384];
  const int tid = threadIdx.x, lane = tid & 63, wave = tid >> 6;
  const int wr = wave >> 1, wc = wave & 1;
  const int fr = lane & 15, fkb = (lane >> 4) * 16, q4 = (lane >> 4) * 4;
  const long bm = (long)blockIdx.y * 128;   // row in [0,8192)
  const long bn = (long)blockIdx.x * 128;   // col in [0,768)
  const int  b  = (int)(bm >> 11);
  const int  tb = (int)(bm & 2047);

  f32x4 acc[4][4] = {};
  core128_bk64(xb + bm * 1024, WqkvT + bn * 1024, 1024, 1024, 16,
               AsB, BsB, acc, tid, wr, wc, fr, fkb);

  if (bn < 256) {
    // Q: sigmoid -> sgQ f32 [8192][256]
#pragma unroll
    for (int n = 0; n < 4; ++n) {
      const int col = (int)bn + wc * 64 + n * 16 + fr;
      const float bb = biascat[col];
#pragma unroll
      for (int m = 0; m < 4; ++m)
#pragma unroll
        for (int r = 0; r < 4; ++r) {
          long row = bm + wr * 64 + m * 16 + q4 + r;
          float v = acc[m][n][r] + bb;
          sgQ[row * 256 + col] = 1.f / (1.f + __expf(-v));
        }
    }
  } else {
    // KV: pair K (even u) with V (odd u) via shfl_xor(1); B2T rows interleaved
#pragma unroll
    for (int n = 0; n < 4; ++n) {
      const int col = (int)bn + wc * 64 + n * 16 + fr;
      const int u   = col - 256;
      const float bb = biascat[col];
      const bool isK = (u & 1) == 0;
      const long rw = (long)b * 512 + u + (isK ? 1 : -1);
#pragma unroll
      for (int m = 0; m < 4; ++m) {
        float v[4], o[4];
#pragma unroll
        for (int r = 0; r < 4; ++r) v[r] = acc[m][n][r] + bb;
#pragma unroll
        for (int r = 0; r < 4; ++r) o[r] = __shfl_xor(v[r], 1);
        ushort4 pk;
        if (isK) {       // den row: exp(K)
          pk.x = f2b(__expf(v[0])); pk.y = f2b(__expf(v[1]));
          pk.z = f2b(__expf(v[2])); pk.w = f2b(__expf(v[3]));
        } else {         // num row: exp(K)*V
          pk.x = f2b(__expf(o[0]) * v[0]); pk.y = f2b(__expf(o[1]) * v[1]);
          pk.z = f2b(__expf(o[2]) * v[2]); pk.w = f2b(__expf(o[3]) * v[3]);
        }
        const int t0 = tb + wr * 64 + m * 16 + q4;
        *(ushort4*)(B2T + rw * 2048 + t0) = pk;
      }
    }
  }
}

// elt2: Yt[m][h] = bf16( sgQ[m][h] * num/den )
__global__ void elt2_kernel(const float* __restrict__ C2, const float* __restrict__ sgQ,
                            unsigned short* __restrict__ Yt) {
  int idx = blockIdx.x * 256 + threadIdx.x;   // 8192*256
  int h = idx & 255, m = idx >> 8;
  int b = m >> 11, tt = m & 2047;
  long p2 = ((long)tt * 2048 + b * 512) >> 1;  // float2 index of (num,den) pair 0
  float2 nd = ((const float2*)C2)[p2 + h];
  Yt[idx] = f2b(sgQ[idx] * nd.x / nd.y);
}

// prep: converts + weight transposes
__global__ void prep_kernel(const float* __restrict__ x, const float* __restrict__ wbias,
                            const float* __restrict__ Wq, const float* __restrict__ Wk,
                            const float* __restrict__ Wv, const float* __restrict__ bq,
                            const float* __restrict__ bk, const float* __restrict__ bv,
                            const float* __restrict__ Wp,
                            unsigned short* __restrict__ xb, unsigned short* __restrict__ ewb,
                            unsigned short* __restrict__ WqkvT, unsigned short* __restrict__ WpT,
                            float* __restrict__ biascat) {
  const int bid = blockIdx.x;
  const int t = threadIdx.x;
  if (bid < 8192) {
    int i = bid * 256 + t;
    float4 v = ((const float4*)x)[i];
    ushort4 o; o.x = f2b(v.x); o.y = f2b(v.y); o.z = f2b(v.z); o.w = f2b(v.w);
    ((ushort4*)xb)[i] = o;
  } else if (bid < 12288) {
    int i = (bid - 8192) * 256 + t;
    float4 v = ((const float4*)wbias)[i];
    ushort4 o;
    o.x = f2b(__expf(v.x)); o.y = f2b(__expf(v.y));
    o.z = f2b(__expf(v.z)); o.w = f2b(__expf(v.w));
    ((ushort4*)ewb)[i] = o;
  } else {
    int idx = (bid - 12288) * 256 + t;
    if (idx < 768 * 1024) {              // cols: n<256 Q_n; 256+2h K_h; 257+2h V_h
      int n = idx >> 10, k = idx & 1023;
      const float* W; int c;
      if (n < 256) { W = Wq; c = n; }
      else { int u = n - 256; c = u >> 1; W = (u & 1) ? Wv : Wk; }
      WqkvT[idx] = f2b(W[k * 256 + c]);
    }
    if (idx < 1024 * 256) {              // WpT[d][h] = Wp[h][d]
      int d = idx >> 8, h = idx & 255;
      WpT[idx] = f2b(Wp[h * 1024 + d]);
    }
    if (idx < 768) {
      float v;
      if (idx < 256) v = bq[idx];
      else { int u = idx - 256; v = (u & 1) ? bv[u >> 1] : bk[u >> 1]; }
      biascat[idx] = v;
    }
  }
}

extern "C" void kernel_launch(void* const* d_in, const int* in_sizes, int n_in,
                              void* d_out, int out_size, void* d_ws, size_t ws_size,
                              hipStream_t stream) {
  const float* x     = (const float*)d_in[0];
  const float* Wq    = (const float*)d_in[1];
  const float* bq    = (const float*)d_in[2];
  const float* Wk    = (const float*)d_in[3];
  const float* bk    = (const float*)d_in[4];
  const float* Wv    = (const float*)d_in[5];
  const float* bv    = (const float*)d_in[6];
  const float* Wp    = (const float*)d_in[7];
  const float* bp    = (const float*)d_in[8];
  const float* wbias = (const float*)d_in[9];

  char* ws = (char*)d_ws;
  unsigned short* xb      = (unsigned short*)(ws + 0);            // 16 MB
  float*          C2      = (float*)(ws + 16777216);              // 16 MB
  unsigned short* ewb     = (unsigned short*)(ws + 33554432);     // 8 MB
  unsigned short* WqkvT   = (unsigned short*)(ws + 41943040);     // 1.5 MB
  unsigned short* WpT     = (unsigned short*)(ws + 43515904);     // 512 KB
  float*          biascat = (float*)(ws + 44040192);              // 4 KB
  float*          sgQ     = (float*)(ws + 44044288);              // 8 MB
  unsigned short* B2T     = (unsigned short*)(ws + 52432896);     // 8 MB
  unsigned short* Yt      = (unsigned short*)(ws + 60821504);     // 4 MB -> 65 MB total
  float* out = (float*)d_out;

  prep_kernel<<<15360, 256, 0, stream>>>(x, wbias, Wq, Wk, Wv, bq, bk, bv, Wp,
                                         xb, ewb, WqkvT, WpT, biascat);
  gemm1_qkv<<<dim3(6, 64), 256, 0, stream>>>(xb, WqkvT, biascat, sgQ, B2T);
  gemm_bt<<<dim3(16, 16), 256, 0, stream>>>(ewb, B2T, C2, nullptr, 2048, 2048, 2048);
  elt2_kernel<<<8192, 256, 0, stream>>>(C2, sgQ, Yt);
  gemm_bt<<<dim3(8, 64), 256, 0, stream>>>(Yt, WpT, out, bp, 8192, 1024, 256);
}

// Round 9
// 186.177 us; speedup vs baseline: 1.1248x; 1.1248x over previous
//
#include <hip/hip_runtime.h>
#include <hip/hip_bf16.h>

// AFT-Full: B=4, T=2048, DIM=1024, HID=256
// GEMM core: 128xBN tile, BK=64, single-buffer LDS, 4 waves (2x2), XOR-swizzled
// LDS (T2 both-sides: linear gload_lds dest + inverse-swizzled global source +
// swizzled ds_read; slot' = slot ^ (row&7), read key = fr&7). R8 showed 6.3M
// bank-conflict cycles from the linear 128B-stride layout; this kills them.
//   prep      : xb=bf16(x); ewb=bf16(exp(wbias)); WqkvT interleaved (0..255=Q,
//               256+2h=K_h, 257+2h=V_h); WpT[d][h]=Wp[h][d]; biascat
//   gemm1_qkv : [8192x768] = xb @ WqkvT^T + biascat, BN=64 (768 blocks, 3/CU).
//               Q cols -> sgQ f32 = sigmoid(q); KV cols -> shfl-pair + LDS-bounce
//               -> coalesced B2T rows b*512+2h = exp(K)*V, b*512+2h+1 = exp(K)
//   gemm2     : C2[z] = ewb @ B2T^T, split-K x2 (512 blocks = 2/CU overlap)
//   elt2      : Yt bf16[8192][256] = sgQ * (Σnum)/(Σden)
//   gemm3     : out = Yt @ WpT^T + bp, BN=128 (512 blocks)
// Workspace: xb 16M | C2 ns*16M | ewb 8M | WqkvT 1.5M | WpT 0.5M | biascat 4K |
// sgQ 8M | B2T 8M | Yt 4M.  ns=2 if ws >= 81803264 else 1.

typedef __attribute__((ext_vector_type(8))) short bf16x8;
typedef __attribute__((ext_vector_type(4))) float f32x4;

static __device__ __forceinline__ unsigned short f2b(float f) {
  __hip_bfloat16 h = __float2bfloat16(f);
  return __builtin_bit_cast(unsigned short, h);
}

static __device__ __forceinline__ void gld16(const void* g, const void* l) {
  __builtin_amdgcn_global_load_lds((const __attribute__((address_space(1))) void*)g,
                                   (__attribute__((address_space(3))) void*)l, 16, 0, 0);
}

// Swizzled BK=64 core. LDS row = 128B = 8 x 16B slots; LDS(row, s) holds
// global(row, s ^ (row&7)).  Staging thread t -> (row = t>>3 (+32i), slot = t&7):
// source slot = (t&7) ^ ((t>>3)&7), LDS dest linear t*16 + 4096*i.
// Fragment read: row = <mult of 8> + fr, want global slot kk*4+g ->
// read LDS slot (kk*4+g) ^ (fr&7).  64 lanes spread uniformly over 8 slots.
template <int BN>
static __device__ __forceinline__ void core_swz(
    const unsigned short* __restrict__ A_blk,
    const unsigned short* __restrict__ Bt_blk,
    long sA, long sB, int nk, char* AsB, char* BsB, f32x4 (&acc)[4][BN / 32],
    int tid, int wr, int wc, int fr, int g)
{
  const int srow = tid >> 3;
  const int sslot = (tid & 7) ^ (srow & 7);
  const unsigned short* ap = A_blk + (long)srow * sA + sslot * 8;
  const unsigned short* bp = Bt_blk + (long)srow * sB + sslot * 8;
  char* la = AsB + tid * 16;
  char* lb = BsB + tid * 16;
  const int xr = fr & 7;              // read-side XOR key (= row&7)

  for (int kt = 0; kt < nk; ++kt) {
    gld16(ap,           la);
    gld16(ap + 32 * sA, la + 4096);
    gld16(ap + 64 * sA, la + 8192);
    gld16(ap + 96 * sA, la + 12288);
    gld16(bp,           lb);
    gld16(bp + 32 * sB, lb + 4096);
    if constexpr (BN == 128) {
      gld16(bp + 64 * sB, lb + 8192);
      gld16(bp + 96 * sB, lb + 12288);
    }
    ap += 64; bp += 64;
    asm volatile("s_waitcnt vmcnt(0)" ::: "memory");
    __syncthreads();

#pragma unroll
    for (int kk = 0; kk < 2; ++kk) {
      const int soff = ((kk * 4 + g) ^ xr) * 16;   // swizzled 16B slot
      bf16x8 av[4], bv[BN / 32];
#pragma unroll
      for (int m = 0; m < 4; ++m)
        av[m] = *(const bf16x8*)(AsB + (wr * 64 + m * 16 + fr) * 128 + soff);
#pragma unroll
      for (int n = 0; n < BN / 32; ++n)
        bv[n] = *(const bf16x8*)(BsB + (wc * (BN / 2) + n * 16 + fr) * 128 + soff);
#pragma unroll
      for (int m = 0; m < 4; ++m)
#pragma unroll
        for (int n = 0; n < BN / 32; ++n)
          acc[m][n] = __builtin_amdgcn_mfma_f32_16x16x32_bf16(av[m], bv[n], acc[m][n], 0, 0, 0);
    }
    __syncthreads();
  }
}

// Generic C = A @ Bt^T (+bias); split-K via blockIdx.z writes C + z*M*N.
__global__ __launch_bounds__(256) void gemm_bt(
    const unsigned short* __restrict__ A, const unsigned short* __restrict__ Bt,
    float* __restrict__ C, const float* __restrict__ bias,
    int M, int N, int K, int Ksub)
{
  __shared__ char AsB[16384];
  __shared__ char BsB[16384];
  const int tid = threadIdx.x, lane = tid & 63, wave = tid >> 6;
  const int wr = wave >> 1, wc = wave & 1;
  const int fr = lane & 15, g = lane >> 4, q4 = g * 4;
  const long bm = (long)blockIdx.y * 128;
  const long bn = (long)blockIdx.x * 128;
  const long k0 = (long)blockIdx.z * Ksub;

  f32x4 acc[4][4] = {};
  core_swz<128>(A + bm * K + k0, Bt + bn * K + k0, K, K, Ksub >> 6,
                AsB, BsB, acc, tid, wr, wc, fr, g);

  float* Cz = C + (long)blockIdx.z * M * (long)N;
  const long crow0 = bm + wr * 64 + q4;
  const long ccol0 = bn + wc * 64 + fr;
#pragma unroll
  for (int n = 0; n < 4; ++n) {
    const long col = ccol0 + n * 16;
    const float bb = bias ? bias[col] : 0.f;
#pragma unroll
    for (int m = 0; m < 4; ++m)
#pragma unroll
      for (int r = 0; r < 4; ++r)
        Cz[(crow0 + m * 16 + r) * (long)N + col] = acc[m][n][r] + bb;
  }
}

// gemm1: QKV projection, BN=64, fused sigmoid / exp / LDS-bounce transpose
__global__ __launch_bounds__(256) void gemm1_qkv(
    const unsigned short* __restrict__ xb, const unsigned short* __restrict__ WqkvT,
    const float* __restrict__ biascat,
    float* __restrict__ sgQ, unsigned short* __restrict__ B2T)
{
  __shared__ char AsB[16384];
  __shared__ char BsB[8192];
  const int tid = threadIdx.x, lane = tid & 63, wave = tid >> 6;
  const int wr = wave >> 1, wc = wave & 1;
  const int fr = lane & 15, g = lane >> 4, q4 = g * 4;
  const long bm = (long)blockIdx.y * 128;   // row in [0,8192)
  const long bn = (long)blockIdx.x * 64;    // col in [0,768)
  const int  b  = (int)(bm >> 11);
  const int  tb = (int)(bm & 2047);

  f32x4 acc[4][2] = {};
  core_swz<64>(xb + bm * 1024, WqkvT + bn * 1024, 1024, 1024, 16,
               AsB, BsB, acc, tid, wr, wc, fr, g);

  if (bn < 256) {
    // Q: sigmoid -> sgQ f32 [8192][256] (64-lane store = 4 rows x 64B, coalesced)
#pragma unroll
    for (int n = 0; n < 2; ++n) {
      const int col = (int)bn + wc * 32 + n * 16 + fr;
      const float bb = biascat[col];
#pragma unroll
      for (int m = 0; m < 4; ++m)
#pragma unroll
        for (int r = 0; r < 4; ++r) {
          long row = bm + wr * 64 + m * 16 + q4 + r;
          float v = acc[m][n][r] + bb;
          sgQ[row * 256 + col] = 1.f / (1.f + __expf(-v));
        }
    }
  } else {
    // KV: pair K (even u) with V (odd u) via shfl_xor(1); bounce through LDS
    // (AsB reused; 64 rows x 256B, 16B-slot XOR swizzle key u&15), then
    // coalesced 256B-row writes to B2T.
#pragma unroll
    for (int n = 0; n < 2; ++n) {
      const int col  = (int)bn + wc * 32 + n * 16 + fr;
      const int u_in = wc * 32 + n * 16 + fr;        // u within block [0,64)
      const float bb = biascat[col];
      const bool isK = (fr & 1) == 0;
      const int u_tgt = u_in + (isK ? 1 : -1);       // row this lane WRITES
#pragma unroll
      for (int m = 0; m < 4; ++m) {
        float v[4], o[4];
#pragma unroll
        for (int r = 0; r < 4; ++r) v[r] = acc[m][n][r] + bb;
#pragma unroll
        for (int r = 0; r < 4; ++r) o[r] = __shfl_xor(v[r], 1);
        ushort4 pk;
        if (isK) {       // den row: exp(K)
          pk.x = f2b(__expf(v[0])); pk.y = f2b(__expf(v[1]));
          pk.z = f2b(__expf(v[2])); pk.w = f2b(__expf(v[3]));
        } else {         // num row: exp(K)*V
          pk.x = f2b(__expf(o[0]) * v[0]); pk.y = f2b(__expf(o[1]) * v[1]);
          pk.z = f2b(__expf(o[2]) * v[2]); pk.w = f2b(__expf(o[3]) * v[3]);
        }
        const int t_local = wr * 64 + m * 16 + q4;           // 8B-aligned in row
        const int slot16  = t_local >> 3;                    // 16B slot of 2B elems
        const int addr = u_tgt * 256 + ((slot16 ^ (u_tgt & 15)) << 4)
                       + ((t_local * 2) & 15);
        *(ushort4*)(AsB + addr) = pk;
      }
    }
    __syncthreads();
    // copy out 16KB: thread t handles units t+256*i; unit -> (u = idx>>4, s = idx&15)
#pragma unroll
    for (int i = 0; i < 4; ++i) {
      int idx = tid + 256 * i;
      int u = idx >> 4, s = idx & 15;
      uint4 val = *(const uint4*)(AsB + u * 256 + ((s ^ (u & 15)) << 4));
      long rw = (long)b * 512 + (bn - 256) + u;
      *(uint4*)(B2T + rw * 2048 + tb + s * 8) = val;
    }
  }
}

// elt2: Yt[m][h] = bf16( sgQ[m][h] * Σz num / Σz den )
__global__ void elt2_kernel(const float* __restrict__ C2, const float* __restrict__ sgQ,
                            unsigned short* __restrict__ Yt, int nslices) {
  int idx = blockIdx.x * 256 + threadIdx.x;   // 8192*256
  int h = idx & 255, m = idx >> 8;
  int b = m >> 11, tt = m & 2047;
  long p2 = ((long)tt * 2048 + b * 512) >> 1;  // float2 index of (num,den) pair 0
  const float2* C22 = (const float2*)C2;
  float num = 0.f, den = 0.f;
  for (int z = 0; z < nslices; ++z) {
    float2 nd = C22[(long)z * 2097152 + p2 + h];
    num += nd.x; den += nd.y;
  }
  Yt[idx] = f2b(sgQ[idx] * num / den);
}

// prep: converts + weight transposes
__global__ void prep_kernel(const float* __restrict__ x, const float* __restrict__ wbias,
                            const float* __restrict__ Wq, const float* __restrict__ Wk,
                            const float* __restrict__ Wv, const float* __restrict__ bq,
                            const float* __restrict__ bk, const float* __restrict__ bv,
                            const float* __restrict__ Wp,
                            unsigned short* __restrict__ xb, unsigned short* __restrict__ ewb,
                            unsigned short* __restrict__ WqkvT, unsigned short* __restrict__ WpT,
                            float* __restrict__ biascat) {
  const int bid = blockIdx.x;
  const int t = threadIdx.x;
  if (bid < 8192) {
    int i = bid * 256 + t;
    float4 v = ((const float4*)x)[i];
    ushort4 o; o.x = f2b(v.x); o.y = f2b(v.y); o.z = f2b(v.z); o.w = f2b(v.w);
    ((ushort4*)xb)[i] = o;
  } else if (bid < 12288) {
    int i = (bid - 8192) * 256 + t;
    float4 v = ((const float4*)wbias)[i];
    ushort4 o;
    o.x = f2b(__expf(v.x)); o.y = f2b(__expf(v.y));
    o.z = f2b(__expf(v.z)); o.w = f2b(__expf(v.w));
    ((ushort4*)ewb)[i] = o;
  } else {
    int idx = (bid - 12288) * 256 + t;
    if (idx < 768 * 1024) {              // cols: n<256 Q_n; 256+2h K_h; 257+2h V_h
      int n = idx >> 10, k = idx & 1023;
      const float* W; int c;
      if (n < 256) { W = Wq; c = n; }
      else { int u = n - 256; c = u >> 1; W = (u & 1) ? Wv : Wk; }
      WqkvT[idx] = f2b(W[k * 256 + c]);
    }
    if (idx < 1024 * 256) {              // WpT[d][h] = Wp[h][d]
      int d = idx >> 8, h = idx & 255;
      WpT[idx] = f2b(Wp[h * 1024 + d]);
    }
    if (idx < 768) {
      float v;
      if (idx < 256) v = bq[idx];
      else { int u = idx - 256; v = (u & 1) ? bv[u >> 1] : bk[u >> 1]; }
      biascat[idx] = v;
    }
  }
}

extern "C" void kernel_launch(void* const* d_in, const int* in_sizes, int n_in,
                              void* d_out, int out_size, void* d_ws, size_t ws_size,
                              hipStream_t stream) {
  const float* x     = (const float*)d_in[0];
  const float* Wq    = (const float*)d_in[1];
  const float* bq    = (const float*)d_in[2];
  const float* Wk    = (const float*)d_in[3];
  const float* bk    = (const float*)d_in[4];
  const float* Wv    = (const float*)d_in[5];
  const float* bv    = (const float*)d_in[6];
  const float* Wp    = (const float*)d_in[7];
  const float* bp    = (const float*)d_in[8];
  const float* wbias = (const float*)d_in[9];

  const int nslices = (ws_size >= 81803264ull) ? 2 : 1;

  char* ws = (char*)d_ws;
  const long rest0 = 16777216 + (long)nslices * 16777216;
  unsigned short* xb      = (unsigned short*)(ws + 0);            // 16 MB
  float*          C2      = (float*)(ws + 16777216);              // ns x 16 MB
  unsigned short* ewb     = (unsigned short*)(ws + rest0);        // 8 MB
  unsigned short* WqkvT   = (unsigned short*)(ws + rest0 + 8388608);
  unsigned short* WpT     = (unsigned short*)(ws + rest0 + 9961472);
  float*          biascat = (float*)(ws + rest0 + 10485760);
  float*          sgQ     = (float*)(ws + rest0 + 10489856);      // 8 MB
  unsigned short* B2T     = (unsigned short*)(ws + rest0 + 18878464); // 8 MB
  unsigned short* Yt      = (unsigned short*)(ws + rest0 + 27267072); // 4 MB
  float* out = (float*)d_out;

  prep_kernel<<<15360, 256, 0, stream>>>(x, wbias, Wq, Wk, Wv, bq, bk, bv, Wp,
                                         xb, ewb, WqkvT, WpT, biascat);
  gemm1_qkv<<<dim3(12, 64), 256, 0, stream>>>(xb, WqkvT, biascat, sgQ, B2T);
  gemm_bt<<<dim3(16, 16, nslices), 256, 0, stream>>>(ewb, B2T, C2, nullptr,
                                                     2048, 2048, 2048, 2048 / nslices);
  elt2_kernel<<<8192, 256, 0, stream>>>(C2, sgQ, Yt, nslices);
  gemm_bt<<<dim3(8, 64, 1), 256, 0, stream>>>(Yt, WpT, out, bp, 8192, 1024, 256, 256);
}